// Round 1
// baseline (1519.567 us; speedup 1.0000x reference)
//
#include <hip/hip_runtime.h>

// Downsample: 3x3 conv (96->48, stride 1, pad 1, no bias) + PixelUnshuffle(2)
// x: (8, 96, 256, 256) fp32; W: (48, 96, 3, 3) fp32; out: (8, 192, 128, 128) fp32
//
// Round 1: fp32 direct conv, LDS-staged input tile, wave-uniform (scalar) weight
// loads, unshuffle folded into store addressing. fp32-VALU-bound by design
// (no fp32 MFMA on CDNA4); baseline before bf16-MFMA rewrite.

#define TW 32      // tile width (conv output coords)
#define TH 8       // tile height
#define CI_CHUNK 16
#define CIN 96
#define COUT 48
#define HW 256

__global__ __launch_bounds__(256) void conv3x3_unshuffle(
    const float* __restrict__ x,
    const float* __restrict__ Wg,
    float* __restrict__ out)
{
    __shared__ float xs[CI_CHUNK][TH + 2][TW + 2];   // 16*10*34*4 = 21.76 KB

    const int tid = threadIdx.x;
    const int tx = tid & 31;        // 0..31 (w within tile)
    const int ty = tid >> 5;        // 0..7  (h within tile)
    const int b  = blockIdx.z;
    const int h0 = blockIdx.y * TH;
    const int w0 = blockIdx.x * TW;

    float acc[COUT];
#pragma unroll
    for (int i = 0; i < COUT; ++i) acc[i] = 0.f;

    const float* xb = x + (size_t)b * CIN * HW * HW;

    for (int ci0 = 0; ci0 < CIN; ci0 += CI_CHUNK) {
        // ---- stage x tile (with halo, zero-padded at image border) into LDS ----
        constexpr int STAGE_N = CI_CHUNK * (TH + 2) * (TW + 2);   // 5440
        for (int idx = tid; idx < STAGE_N; idx += 256) {
            int ci  = idx / ((TH + 2) * (TW + 2));
            int rem = idx - ci * ((TH + 2) * (TW + 2));
            int r   = rem / (TW + 2);
            int c   = rem - r * (TW + 2);
            int gh  = h0 + r - 1;
            int gw  = w0 + c - 1;
            float v = 0.f;
            if ((unsigned)gh < HW && (unsigned)gw < HW)
                v = xb[(size_t)(ci0 + ci) * HW * HW + gh * HW + gw];
            xs[ci][r][c] = v;
        }
        __syncthreads();

        // ---- accumulate over this ci chunk ----
#pragma unroll 1
        for (int ci = 0; ci < CI_CHUNK; ++ci) {
            float xv[9];
#pragma unroll
            for (int dy = 0; dy < 3; ++dy)
#pragma unroll
                for (int dx = 0; dx < 3; ++dx)
                    xv[dy * 3 + dx] = xs[ci][ty + dy][tx + dx];

            const int wci = ci0 + ci;
            // wave-uniform weight addresses -> scalar loads (s_load), SGPR operand in v_fma
#pragma unroll
            for (int co = 0; co < COUT; ++co) {
                const float* w = Wg + (co * CIN + wci) * 9;
                float a = acc[co];
                a = fmaf(xv[0], w[0], a);
                a = fmaf(xv[1], w[1], a);
                a = fmaf(xv[2], w[2], a);
                a = fmaf(xv[3], w[3], a);
                a = fmaf(xv[4], w[4], a);
                a = fmaf(xv[5], w[5], a);
                a = fmaf(xv[6], w[6], a);
                a = fmaf(xv[7], w[7], a);
                a = fmaf(xv[8], w[8], a);
                acc[co] = a;
            }
        }
        __syncthreads();
    }

    // ---- write out, folding PixelUnshuffle(2) into the addressing ----
    // conv pixel (oh, ow) of channel co  ->  out[b][co*4 + (oh&1)*2 + (ow&1)][oh>>1][ow>>1]
    const int oh  = h0 + ty;
    const int ow  = w0 + tx;
    const int sub = ((oh & 1) << 1) | (ow & 1);
    const size_t obase =
        (((size_t)b * (COUT * 4) + sub) * (HW / 2) + (oh >> 1)) * (HW / 2) + (ow >> 1);
#pragma unroll
    for (int co = 0; co < COUT; ++co)
        out[obase + (size_t)co * 4 * (HW / 2) * (HW / 2)] = acc[co];
}

extern "C" void kernel_launch(void* const* d_in, const int* in_sizes, int n_in,
                              void* d_out, int out_size, void* d_ws, size_t ws_size,
                              hipStream_t stream) {
    const float* x  = (const float*)d_in[0];   // 8*96*256*256
    const float* Wg = (const float*)d_in[1];   // 48*96*3*3
    float* out      = (float*)d_out;           // 8*192*128*128

    dim3 grid(HW / TW, HW / TH, 8);            // (8, 32, 8) = 2048 blocks
    dim3 block(256);
    conv3x3_unshuffle<<<grid, block, 0, stream>>>(x, Wg, out);
}

// Round 2
// 579.019 us; speedup vs baseline: 2.6244x; 2.6244x over previous
//
#include <hip/hip_runtime.h>

// Downsample: 3x3 conv (96->48, s1, p1, no bias) + PixelUnshuffle(2), fused.
// x: (8,96,256,256) fp32; W: (48,96,3,3) fp32; out: (8,192,128,128) fp32.
//
// R2: bf16 MFMA implicit GEMM. Conv = 9 shifted GEMMs C[co][pix] += W.x over
// ci (K), K-chunks of 32 = one mfma_f32_16x16x32_bf16 k-step.
// Per block (256 thr = 4 waves): 8h x 32w pixel tile, all 48 co.
//   - x staged per ci-chunk to LDS as [halo_pix][ci] (transposed, bf16,
//     ci-stride padded to 40 halfs: 16B-aligned b128 frag reads, even banks)
//   - W transformed per ci-chunk into MFMA A-frag blob (lane-contiguous 16B,
//     conflict-free reads; W global reads are L2-resident)
//   - wave tile: 4 pixel-frags (16 pix) x 3 co-frags (16 co) = 48 acc VGPRs
// LDS 27200 + 27648 = 54848 B -> 2 blocks/CU. HBM-bound by design (~58us floor).

typedef __attribute__((ext_vector_type(8))) short bf16x8;   // 8 bf16 (4 VGPRs)
typedef __attribute__((ext_vector_type(4))) float f32x4;    // MFMA C/D

#define CIN 96
#define COUT 48
#define HW 256
#define TH 8
#define TW 32
#define HALO_H (TH + 2)
#define HALO_W (TW + 2)
#define CC 32            // ci per chunk = one MFMA k-step
#define CIPAD 40         // padded ci stride (halfs): 80B -> 16B-aligned, even banks
#define NFRAG 27         // A-frags per chunk: 9 (dy,dx) x 3 co-tiles

static __device__ __forceinline__ short f2bf(float f) {
    unsigned u = __builtin_bit_cast(unsigned, f);
    unsigned r = (u + 0x7fffu + ((u >> 16) & 1u)) >> 16;   // RNE
    return (short)r;
}

__global__ __launch_bounds__(256, 2) void conv3x3_unshuffle_mfma(
    const float* __restrict__ x,
    const float* __restrict__ Wg,
    float* __restrict__ out)
{
    __shared__ short xs[HALO_H * HALO_W * CIPAD];   // 13600 halfs = 27200 B
    __shared__ short wb[NFRAG * 64 * 8];            // 13824 halfs = 27648 B

    const int tid  = threadIdx.x;
    const int lane = tid & 63;
    const int wv   = tid >> 6;          // wave 0..3
    const int b    = blockIdx.z;
    const int h0   = blockIdx.y * TH;
    const int w0   = blockIdx.x * TW;

    const float* xb = x + (size_t)b * CIN * HW * HW;

    f32x4 acc[4][3];
#pragma unroll
    for (int pt = 0; pt < 4; ++pt)
#pragma unroll
        for (int ct = 0; ct < 3; ++ct)
            acc[pt][ct] = (f32x4){0.f, 0.f, 0.f, 0.f};

    for (int cc = 0; cc < CIN / CC; ++cc) {
        // ---- stage x chunk: global [ci][h][w] fp32 -> LDS [halo_pix][ci] bf16 ----
        constexpr int XN = CC * HALO_H * HALO_W;     // 10880
        for (int idx = tid; idx < XN; idx += 256) {
            int ci  = idx / (HALO_H * HALO_W);
            int rem = idx - ci * (HALO_H * HALO_W);
            int r   = rem / HALO_W;
            int c   = rem - r * HALO_W;              // lanes -> consecutive c (coalesced)
            int gh  = h0 + r - 1;
            int gw  = w0 + c - 1;
            float v = 0.f;
            if ((unsigned)gh < HW && (unsigned)gw < HW)
                v = xb[(size_t)(cc * CC + ci) * HW * HW + gh * HW + gw];
            xs[(r * HALO_W + c) * CIPAD + ci] = f2bf(v);
        }

        // ---- transform W chunk into A-frag blob ----
        // frag f = d*3 + cotile; lane = (co&15) | ((ci_local>>3)<<4); j = ci_local&7
        for (int s = tid; s < COUT * CC; s += 256) {
            int co = s >> 5;                 // s / 32
            int cl = s & 31;                 // ci_local
            const float* wp = Wg + ((size_t)co * CIN + cc * CC + cl) * 9;
            int lw = (co & 15) | ((cl >> 3) << 4);
            int j  = cl & 7;
#pragma unroll
            for (int d = 0; d < 9; ++d) {
                int f = d * 3 + (co >> 4);
                wb[(f * 64 + lw) * 8 + j] = f2bf(wp[d]);
            }
        }
        __syncthreads();

        // ---- 9 shifted GEMM k-steps ----
        for (int d = 0; d < 9; ++d) {
            const int dy = d / 3, dx = d - 3 * (d / 3);
            bf16x8 af[3];
#pragma unroll
            for (int ct = 0; ct < 3; ++ct)
                af[ct] = *(const bf16x8*)&wb[((d * 3 + ct) * 64 + lane) * 8];
#pragma unroll
            for (int pt = 0; pt < 4; ++pt) {
                int r  = 2 * wv + (pt >> 1);         // tile row 0..7
                int hr = r + dy;                     // halo row
                int hc = (pt & 1) * 16 + (lane & 15) + dx;
                bf16x8 bf = *(const bf16x8*)&xs[(hr * HALO_W + hc) * CIPAD + (lane >> 4) * 8];
#pragma unroll
                for (int ct = 0; ct < 3; ++ct)
                    acc[pt][ct] = __builtin_amdgcn_mfma_f32_16x16x32_bf16(
                        af[ct], bf, acc[pt][ct], 0, 0, 0);
            }
        }
        __syncthreads();
    }

    // ---- epilogue: PixelUnshuffle folded into addressing ----
    // C/D layout: col(pix) = lane&15, row(co) = (lane>>4)*4 + reg
#pragma unroll
    for (int pt = 0; pt < 4; ++pt) {
        int oh = h0 + 2 * wv + (pt >> 1);
        int ow = w0 + (pt & 1) * 16 + (lane & 15);
        int sub = ((oh & 1) << 1) | (ow & 1);
        size_t pixoff = (size_t)(oh >> 1) * (HW / 2) + (ow >> 1);
#pragma unroll
        for (int ct = 0; ct < 3; ++ct) {
#pragma unroll
            for (int e = 0; e < 4; ++e) {
                int co = ct * 16 + (lane >> 4) * 4 + e;
                out[((size_t)b * (COUT * 4) + co * 4 + sub) * (HW / 2) * (HW / 2) + pixoff] =
                    acc[pt][ct][e];
            }
        }
    }
}

extern "C" void kernel_launch(void* const* d_in, const int* in_sizes, int n_in,
                              void* d_out, int out_size, void* d_ws, size_t ws_size,
                              hipStream_t stream) {
    const float* x  = (const float*)d_in[0];   // 8*96*256*256
    const float* Wg = (const float*)d_in[1];   // 48*96*3*3
    float* out      = (float*)d_out;           // 8*192*128*128

    dim3 grid(HW / TW, HW / TH, 8);            // (8, 32, 8) = 2048 blocks
    dim3 block(256);
    conv3x3_unshuffle_mfma<<<grid, block, 0, stream>>>(x, Wg, out);
}

// Round 3
// 355.621 us; speedup vs baseline: 4.2730x; 1.6282x over previous
//
#include <hip/hip_runtime.h>

// Downsample: 3x3 conv (96->48, s1, p1, no bias) + PixelUnshuffle(2), fused.
// x: (8,96,256,256) fp32; W: (48,96,3,3) fp32; out: (8,192,128,128) fp32.
//
// R3 vs R2 (369us, occupancy 23%, latency-bound):
//  - W frag blob precomputed ONCE into d_ws by a tiny kernel; main kernel
//    reads A-frags from global (L2-resident, coalesced dwordx4, next-d
//    prefetch) -> no wb LDS, no per-block transform.
//  - LDS = xs only (27.2 KB) -> 5 blocks/CU by LDS; __launch_bounds__(256,4).
//  - Staging: each lane packs 8 ci x 1 pix -> 8 coalesced dword loads +
//    ONE ds_write_b128 (lane stride 80B = odd*16B -> ~conflict-free),
//    replacing 8 b16 writes with 8-way conflicts.

typedef __attribute__((ext_vector_type(8))) short bf16x8;   // 8 bf16 (4 VGPRs)
typedef __attribute__((ext_vector_type(4))) float f32x4;    // MFMA C/D
typedef __attribute__((ext_vector_type(4))) unsigned uint4v;

#define CIN 96
#define COUT 48
#define HW 256
#define TH 8
#define TW 32
#define HALO_H (TH + 2)       // 10
#define HALO_W (TW + 2)       // 34
#define NPIX (HALO_H * HALO_W) // 340
#define CC 32                 // ci per chunk = one MFMA k-step
#define CIPAD 40              // padded ci stride (halfs): 80B = odd*16B

static __device__ __forceinline__ unsigned bfbits(float f) {
    unsigned u = __builtin_bit_cast(unsigned, f);
    return (u + 0x7fffu + ((u >> 16) & 1u)) >> 16;   // RNE
}
static __device__ __forceinline__ unsigned packbf(float lo, float hi) {
    return (bfbits(lo) & 0xffffu) | (bfbits(hi) << 16);
}

// ---- kernel 1: W (48,96,3,3) fp32 -> MFMA A-frag blob bf16 in d_ws ----
// blob[cc][d][ct][lane][j], cc=ci>>5, d=3x3 tap, ct=co>>4,
// lane=(co&15)|((cl>>3)<<4), j=cl&7   (cl = ci&31). 3*9*3*64*8 halfs = 82944 B
__global__ __launch_bounds__(256) void wtransform(
    const float* __restrict__ Wg, short* __restrict__ blob)
{
    int t = blockIdx.x * 256 + threadIdx.x;          // = (co*96+ci)*9+d
    if (t >= COUT * CIN * 9) return;
    int co  = t / (CIN * 9);
    int rem = t - co * (CIN * 9);
    int ci  = rem / 9;
    int d   = rem - ci * 9;
    int cc  = ci >> 5, cl = ci & 31;
    int ct  = co >> 4;
    int lane = (co & 15) | ((cl >> 3) << 4);
    int j   = cl & 7;
    blob[((((cc * 9 + d) * 3 + ct) * 64 + lane) * 8) + j] = (short)bfbits(Wg[t]);
}

// ---- kernel 2: conv + unshuffle ----
__global__ __launch_bounds__(256, 4) void conv3x3_unshuffle_mfma(
    const float* __restrict__ x,
    const short* __restrict__ wblob,
    float* __restrict__ out)
{
    __shared__ short xs[NPIX * CIPAD];               // 13600 halfs = 27200 B

    const int tid  = threadIdx.x;
    const int lane = tid & 63;
    const int wv   = tid >> 6;          // wave 0..3
    const int b    = blockIdx.z;
    const int h0   = blockIdx.y * TH;
    const int w0   = blockIdx.x * TW;

    const float* xb = x + (size_t)b * CIN * HW * HW;

    f32x4 acc[4][3];
#pragma unroll
    for (int pt = 0; pt < 4; ++pt)
#pragma unroll
        for (int ct = 0; ct < 3; ++ct)
            acc[pt][ct] = (f32x4){0.f, 0.f, 0.f, 0.f};

    for (int cc = 0; cc < CIN / CC; ++cc) {
        // ---- stage x chunk: 8 ci x 1 pix per task -> one ds_write_b128 ----
        constexpr int TASKS = 4 * NPIX;              // 1360
        for (int t = tid; t < TASKS; t += 256) {
            int cig = t / NPIX;                      // 0..3 (ci group of 8)
            int p   = t - cig * NPIX;                // 0..339, lanes->consecutive pix
            int r   = p / HALO_W;
            int c   = p - r * HALO_W;
            int gh  = h0 + r - 1;
            int gw  = w0 + c - 1;
            float v[8];
#pragma unroll
            for (int j = 0; j < 8; ++j) v[j] = 0.f;
            if (((unsigned)gh < HW) & ((unsigned)gw < HW)) {
                const float* src = xb + (size_t)(cc * CC + cig * 8) * HW * HW + gh * HW + gw;
#pragma unroll
                for (int j = 0; j < 8; ++j) v[j] = src[(size_t)j * HW * HW];
            }
            uint4v pk;
            pk.x = packbf(v[0], v[1]);
            pk.y = packbf(v[2], v[3]);
            pk.z = packbf(v[4], v[5]);
            pk.w = packbf(v[6], v[7]);
            *(uint4v*)&xs[p * CIPAD + cig * 8] = pk; // byte addr = 80p+16cig: 16B aligned
        }
        __syncthreads();

        // ---- 9 shifted GEMM k-steps; A-frags from global blob, prefetched ----
        const short* wc = wblob + (size_t)cc * 9 * 3 * 512;   // 512 halfs per frag
        bf16x8 afc[3];
#pragma unroll
        for (int ct = 0; ct < 3; ++ct)
            afc[ct] = *(const bf16x8*)(wc + ct * 512 + lane * 8);

#pragma unroll
        for (int d = 0; d < 9; ++d) {
            bf16x8 afn[3];
            if (d < 8) {
#pragma unroll
                for (int ct = 0; ct < 3; ++ct)
                    afn[ct] = *(const bf16x8*)(wc + ((d + 1) * 3 + ct) * 512 + lane * 8);
            }
            const int dy = d / 3, dx = d - 3 * (d / 3);
            bf16x8 bfv[4];
#pragma unroll
            for (int pt = 0; pt < 4; ++pt) {
                int hr = 2 * wv + (pt >> 1) + dy;
                int hc = (pt & 1) * 16 + (lane & 15) + dx;
                bfv[pt] = *(const bf16x8*)&xs[(hr * HALO_W + hc) * CIPAD + (lane >> 4) * 8];
            }
#pragma unroll
            for (int pt = 0; pt < 4; ++pt)
#pragma unroll
                for (int ct = 0; ct < 3; ++ct)
                    acc[pt][ct] = __builtin_amdgcn_mfma_f32_16x16x32_bf16(
                        afc[ct], bfv[pt], acc[pt][ct], 0, 0, 0);
#pragma unroll
            for (int ct = 0; ct < 3; ++ct) afc[ct] = afn[ct];
        }
        __syncthreads();
    }

    // ---- epilogue: PixelUnshuffle folded into addressing ----
    // C/D layout: col(pix) = lane&15, row(co) = (lane>>4)*4 + reg
#pragma unroll
    for (int pt = 0; pt < 4; ++pt) {
        int oh = h0 + 2 * wv + (pt >> 1);
        int ow = w0 + (pt & 1) * 16 + (lane & 15);
        int sub = ((oh & 1) << 1) | (ow & 1);
        size_t pixoff = (size_t)(oh >> 1) * (HW / 2) + (ow >> 1);
#pragma unroll
        for (int ct = 0; ct < 3; ++ct) {
#pragma unroll
            for (int e = 0; e < 4; ++e) {
                int co = ct * 16 + (lane >> 4) * 4 + e;
                out[((size_t)b * (COUT * 4) + co * 4 + sub) * (HW / 2) * (HW / 2) + pixoff] =
                    acc[pt][ct][e];
            }
        }
    }
}

extern "C" void kernel_launch(void* const* d_in, const int* in_sizes, int n_in,
                              void* d_out, int out_size, void* d_ws, size_t ws_size,
                              hipStream_t stream) {
    const float* x  = (const float*)d_in[0];   // 8*96*256*256
    const float* Wg = (const float*)d_in[1];   // 48*96*3*3
    float* out      = (float*)d_out;           // 8*192*128*128
    short* blob     = (short*)d_ws;            // 82944 B frag blob

    wtransform<<<(COUT * CIN * 9 + 255) / 256, 256, 0, stream>>>(Wg, blob);

    dim3 grid(HW / TW, HW / TH, 8);            // (8, 32, 8) = 2048 blocks
    conv3x3_unshuffle_mfma<<<grid, dim3(256), 0, stream>>>(x, blob, out);
}